// Round 3
// baseline (326.277 us; speedup 1.0000x reference)
//
#include <hip/hip_runtime.h>
#include <math.h>

#define SEQ    2048
#define EMBED  1024
#define HEADS  16
#define HDIM   64
#define BATCH  4
#define ROWS   (BATCH * SEQ)    // 8192
#define BH     (BATCH * HEADS)  // 64

typedef _Float16 f16;
typedef __attribute__((ext_vector_type(8))) _Float16 f16x8;
typedef __attribute__((ext_vector_type(4))) _Float16 f16x4;
typedef __attribute__((ext_vector_type(4))) float    f32x4;

#define LOG2E_10 0.14426950408889634f   // log2(e)/10

// fast 2^x / log2(x) via the HW transcendental unit
__device__ __forceinline__ float fast_exp2(float x) { return __builtin_amdgcn_exp2f(x); }
__device__ __forceinline__ float fast_log2(float x) { return __builtin_amdgcn_logf(x); }

// async global->LDS copy, 16B per lane. LDS dest = uniform base + lane*16.
__device__ __forceinline__ void async16(void* l, const void* g) {
    __builtin_amdgcn_global_load_lds(
        (__attribute__((address_space(1))) void*)(uintptr_t)g,
        (__attribute__((address_space(3))) void*)(uint32_t)(uintptr_t)l,
        16, 0, 0);
}
// 4B per lane (for small fp32 vectors like lg tiles)
__device__ __forceinline__ void async4(void* l, const void* g) {
    __builtin_amdgcn_global_load_lds(
        (__attribute__((address_space(1))) void*)(uintptr_t)g,
        (__attribute__((address_space(3))) void*)(uint32_t)(uintptr_t)l,
        4, 0, 0);
}

__device__ __forceinline__ f32x4 mfma16(f16x8 a, f16x8 b, f32x4 c) {
    return __builtin_amdgcn_mfma_f32_16x16x32_f16(a, b, c, 0, 0, 0);
}

// ---------------------------------------------------------------------------
// Kernel 0: fp32 -> fp16 convert. x -> xh [8192][1024]; Wq/Wk/Wv -> Wh
// concatenated [3072][1024]. Memory-bound, ~15us.
// ---------------------------------------------------------------------------
#define NX4 (ROWS * EMBED / 4)          // 2097152
#define NW4 (EMBED * EMBED / 4)         // 262144
__global__ __launch_bounds__(256) void cvt_kernel(
    const float* __restrict__ x,
    const float* __restrict__ Wq, const float* __restrict__ Wk,
    const float* __restrict__ Wv,
    f16* __restrict__ xh, f16* __restrict__ Wh)
{
    int i = blockIdx.x * 256 + threadIdx.x;
    const float4* src; f16* dst; int j;
    if (i < NX4)              { src = (const float4*)x;  dst = xh;                j = i; }
    else if (i < NX4 + NW4)   { src = (const float4*)Wq; dst = Wh;                j = i - NX4; }
    else if (i < NX4 + 2*NW4) { src = (const float4*)Wk; dst = Wh + EMBED*EMBED;  j = i - NX4 - NW4; }
    else                      { src = (const float4*)Wv; dst = Wh + 2*EMBED*EMBED;j = i - NX4 - 2*NW4; }
    float4 v = src[j];
    f16x4 h;
    h[0] = (f16)v.x; h[1] = (f16)v.y; h[2] = (f16)v.z; h[3] = (f16)v.w;
    *(f16x4*)(dst + (size_t)j * 4) = h;
}

// ---------------------------------------------------------------------------
// Kernel 1: fused QKV projection GEMM (f16 MFMA).
// C[8192][3072] = xh @ Wh^T + bias. 128x128 tile, BK=32, global_load_lds w=16.
// Pipelined: double-buffered LDS, stage(t+1) issued before compute(t), ONE
// barrier per K-step (T3 minimum recipe). 64B rows conflict-free, no swizzle.
// Epilogue: Q,K -> [bh][s][d] fp16; V -> transposed Vt [bh][d][s] fp16.
// A-panel reuse is naturally XCD-local (ids stride 64 across y).
// ---------------------------------------------------------------------------
__global__ __launch_bounds__(256) void proj_kernel(
    const f16* __restrict__ A,   // [8192][1024]
    const f16* __restrict__ W,   // [3072][1024]
    const float* __restrict__ bq, const float* __restrict__ bk,
    const float* __restrict__ bv,
    f16* __restrict__ Qh, f16* __restrict__ Kh, f16* __restrict__ Vt)
{
    __shared__ f16 As[2][128 * 32];   // [row][32k], rows 64B (glds layout)
    __shared__ f16 Bs[2][128 * 32];

    const int t = threadIdx.x, wv = t >> 6, lane = t & 63;
    const int lm = lane & 15, quad = lane >> 4;
    const int r0 = blockIdx.x * 128, c0 = blockIdx.y * 128;
    const int wm = wv & 1, wn = wv >> 1;

    // staging: each wave stages 32 rows of A and B (2 x 16-row instructions)
    const int srow = wv * 32 + (lane >> 2);
    const int sch  = (lane & 3) * 8;     // f16 units (16B chunks)
    const f16* gA = A + (size_t)(r0 + srow) * EMBED + sch;
    const f16* gB = W + (size_t)(c0 + srow) * EMBED + sch;
    const int lofs = wv * 1024;

    f32x4 acc[4][4];
#pragma unroll
    for (int i = 0; i < 4; ++i)
#pragma unroll
        for (int j = 0; j < 4; ++j) acc[i][j] = (f32x4){0.f, 0.f, 0.f, 0.f};

    // prologue: stage K-step 0 into buffer 0
    async16(&As[0][lofs],       gA);
    async16(&As[0][lofs + 512], gA + 16 * EMBED);
    async16(&Bs[0][lofs],       gB);
    async16(&Bs[0][lofs + 512], gB + 16 * EMBED);
    __syncthreads();

    for (int it = 0; it < EMBED / 32; ++it) {
        const int cur = it & 1, nxt = cur ^ 1;
        if (it + 1 < EMBED / 32) {
            const int kk = (it + 1) * 32;
            async16(&As[nxt][lofs],       gA + kk);
            async16(&As[nxt][lofs + 512], gA + 16 * EMBED + kk);
            async16(&Bs[nxt][lofs],       gB + kk);
            async16(&Bs[nxt][lofs + 512], gB + 16 * EMBED + kk);
        }
        f16x8 af[4], bf[4];
#pragma unroll
        for (int i = 0; i < 4; ++i)
            af[i] = *(const f16x8*)&As[cur][(wm * 64 + i * 16 + lm) * 32 + quad * 8];
#pragma unroll
        for (int i = 0; i < 4; ++i)
            bf[i] = *(const f16x8*)&Bs[cur][(wn * 64 + i * 16 + lm) * 32 + quad * 8];
#pragma unroll
        for (int mi = 0; mi < 4; ++mi)
#pragma unroll
            for (int ni = 0; ni < 4; ++ni)
                acc[mi][ni] = mfma16(af[mi], bf[ni], acc[mi][ni]);
        __syncthreads();   // drains stage vmcnt (after compute) + buffer reuse
    }

    // epilogue: bias + cvt + scatter into attention layouts
    const int z = c0 >> 10;              // 0=Q 1=K 2=V (128 | 1024 so no straddle)
    const float* bias = (z == 0) ? bq : (z == 1) ? bk : bv;
#pragma unroll
    for (int ni = 0; ni < 4; ++ni) {
        int col = c0 + wn * 64 + ni * 16 + lm;
        int cz  = col & 1023;
        float bb = bias[cz];
        int h = cz >> 6, d = cz & 63;
#pragma unroll
        for (int mi = 0; mi < 4; ++mi) {
            int rbase = r0 + wm * 64 + mi * 16 + quad * 4;
            int b = rbase >> 11, s = rbase & 2047;   // 4 rows stay in same b
            if (z < 2) {
                f16* O = (z == 0) ? Qh : Kh;
                size_t base = ((size_t)(b * HEADS + h) * SEQ + s) * HDIM + d;
#pragma unroll
                for (int r = 0; r < 4; ++r)
                    O[base + (size_t)r * HDIM] = (f16)(acc[mi][ni][r] + bb);
            } else {
                f16x4 pk;
#pragma unroll
                for (int r = 0; r < 4; ++r) pk[r] = (f16)(acc[mi][ni][r] + bb);
                *(f16x4*)&Vt[((size_t)(b * HEADS + h) * HDIM + d) * SEQ + s] = pk;
            }
        }
    }
}

// XCD swizzle decode for the two attention kernels: 1024 blocks, 8 XCDs.
// d = xcd + 8*(qx + 16*ygrp)  ->  all 16 q/k-blocks of a bh land on one XCD
// (hardware round-robins linear wgid % 8 across XCDs). Bijective.
__device__ __forceinline__ void xcd_decode(int d, int& bh, int& x128) {
    int xcd  = d & 7;
    int r    = d >> 3;
    x128     = (r & 15) * 128;
    bh       = (r >> 4) * 8 + xcd;
}

// ---------------------------------------------------------------------------
// Kernel 2: column stats. lg[bh][k] = 10 - log2( sum_q exp(S[q,k]/10) ).
// (out_kernel consumes this as an exp2 bias: exp(S/10)*1024/colsum
//  == exp2(S*log2e/10 + lg).)
// 1024 blocks (XCD-swizzled): block owns 128 k-cols; K-frags pinned in regs;
// q swept in 64-row double-buffered LDS tiles, pipelined, 1 barrier/iter.
// 128B-row tiles are chunk-XOR-swizzled (T2 via pre-swizzled global source).
// ---------------------------------------------------------------------------
__global__ __launch_bounds__(256) void stats_kernel(
    const f16* __restrict__ Qh, const f16* __restrict__ Kh,
    float* __restrict__ lgv)
{
    __shared__ f16 Ks[128 * 64];      // [kcol][d] rows 128B, chunk-swizzled
    __shared__ f16 Qs[2][64 * 64];    // [q][d], chunk-swizzled, double-buffered

    const int t = threadIdx.x, wv = t >> 6, lane = t & 63;
    const int lm = lane & 15, quad = lane >> 4;
    int bh, k0;
    xcd_decode(blockIdx.x, bh, k0);
    const int grow = lane >> 3;                      // row within 8-row group
    const int gsw  = ((lane & 7) ^ grow) * 8;        // swizzled 16B source chunk
    const int rs   = lm & 7;                         // read-side row swizzle key
    const size_t base = (size_t)bh * SEQ * HDIM;

    // prologue: stage K panel + Q tile 0
#pragma unroll
    for (int i = 0; i < 4; ++i) {
        int g = wv * 4 + i;
        async16(Ks + g * 512, Kh + base + (size_t)(k0 + g * 8 + grow) * HDIM + gsw);
    }
#pragma unroll
    for (int i = 0; i < 2; ++i) {
        int g = wv * 2 + i;
        async16(&Qs[0][g * 512], Qh + base + (size_t)(g * 8 + grow) * HDIM + gsw);
    }
    __syncthreads();

    f16x8 kf[2][2];   // [coltile][dstep] -- stays in registers all sweep
#pragma unroll
    for (int ct = 0; ct < 2; ++ct)
#pragma unroll
        for (int ds = 0; ds < 2; ++ds)
            kf[ct][ds] = *(const f16x8*)&Ks[(wv * 32 + ct * 16 + lm) * 64
                                            + (((ds * 4 + quad) ^ rs) << 3)];

    float cs0 = 0.f, cs1 = 0.f;
    for (int it = 0; it < SEQ / 64; ++it) {
        const int cur = it & 1, nxt = cur ^ 1;
        if (it + 1 < SEQ / 64) {
            const int q0 = (it + 1) * 64;
#pragma unroll
            for (int i = 0; i < 2; ++i) {
                int g = wv * 2 + i;
                async16(&Qs[nxt][g * 512],
                        Qh + base + (size_t)(q0 + g * 8 + grow) * HDIM + gsw);
            }
        }
#pragma unroll
        for (int qt = 0; qt < 4; ++qt) {
            f16x8 a0 = *(const f16x8*)&Qs[cur][(qt * 16 + lm) * 64 + ((quad ^ rs) << 3)];
            f16x8 a1 = *(const f16x8*)&Qs[cur][(qt * 16 + lm) * 64 + (((4 + quad) ^ rs) << 3)];
            f32x4 c0v = (f32x4){0.f, 0.f, 0.f, 0.f};
            f32x4 c1v = (f32x4){0.f, 0.f, 0.f, 0.f};
            c0v = mfma16(a0, kf[0][0], c0v); c0v = mfma16(a1, kf[0][1], c0v);
            c1v = mfma16(a0, kf[1][0], c1v); c1v = mfma16(a1, kf[1][1], c1v);
#pragma unroll
            for (int r = 0; r < 4; ++r) {
                cs0 += fast_exp2(c0v[r] * LOG2E_10);
                cs1 += fast_exp2(c1v[r] * LOG2E_10);
            }
        }
        __syncthreads();   // drains stage vmcnt + buffer reuse
    }
    // reduce the quad dimension (rows of the C tiles) across lanes
    cs0 += __shfl_xor(cs0, 16, 64); cs0 += __shfl_xor(cs0, 32, 64);
    cs1 += __shfl_xor(cs1, 16, 64); cs1 += __shfl_xor(cs1, 32, 64);
    if (quad == 0) {
        lgv[(size_t)bh * SEQ + k0 + wv * 32 + lm]      = 10.0f - fast_log2(cs0);
        lgv[(size_t)bh * SEQ + k0 + wv * 32 + 16 + lm] = 10.0f - fast_log2(cs1);
    }
}

// ---------------------------------------------------------------------------
// Kernel 3: out[q,d] = (1/1024) * sum_k P''[q,k] * V[k,d],
//           P'' = exp2(S*log2e/10 + lg[k])  (fp16, range [6e-3, 20]).
// 1024 blocks (XCD-swizzled): block = 128 q rows (32/wave), k swept in
// double-buffered 64-tiles, pipelined, 1 barrier/iter.
// Computes S^T = K.Q^T so C-layout rows = k -> pack 4 consecutive-k P vals
// into ds_write_b64 into padded (72 f16/row) per-wave P region; then P @ Vt.
// Ks/Vs/Q-staging 128B-row tiles are chunk-XOR-swizzled; P (144B rows) is
// naturally conflict-free and stays linear.
// ---------------------------------------------------------------------------
__global__ __launch_bounds__(256) void out_kernel(
    const f16* __restrict__ Qh, const f16* __restrict__ Kh,
    const f16* __restrict__ Vt, const float* __restrict__ lgv,
    float* __restrict__ out)
{
    __shared__ f16 Ps[4 * 32 * 72];   // Q staging (swizzled) then P (padded 72)
    __shared__ f16 Ks[2][64 * 64];    // [k][d], chunk-swizzled
    __shared__ f16 Vs[2][64 * 64];    // [d][s-chunk] (from Vt), chunk-swizzled
    __shared__ float Ls[2][64];

    const int t = threadIdx.x, wv = t >> 6, lane = t & 63;
    const int lm = lane & 15, quad = lane >> 4;
    int bh, q0;
    xcd_decode(blockIdx.x, bh, q0);
    const int b = bh >> 4, h = bh & 15;
    const int grow = lane >> 3;
    const int gsw  = ((lane & 7) ^ grow) * 8;        // swizzled 16B source chunk
    const int rs   = lm & 7;                         // read-side row swizzle key
    const size_t base = (size_t)bh * SEQ * HDIM;   // same stride for Qh/Kh/Vt

    // prologue: stage Q[128][64] (wave stages exactly its own 32 rows),
    // plus K/V tile 0 and lg tile 0
#pragma unroll
    for (int i = 0; i < 4; ++i) {
        int g = wv * 4 + i;
        async16(Ps + g * 512, Qh + base + (size_t)(q0 + g * 8 + grow) * HDIM + gsw);
    }
#pragma unroll
    for (int i = 0; i < 2; ++i) {
        int g = wv * 2 + i;
        async16(&Ks[0][g * 512], Kh + base + (size_t)(g * 8 + grow) * HDIM + gsw);
        async16(&Vs[0][g * 512], Vt + base + (size_t)(g * 8 + grow) * SEQ + gsw);
    }
    if (wv == 0) async4(&Ls[0][0], lgv + (size_t)bh * SEQ + lane);
    __syncthreads();

    f16x8 qa[2][2];   // Q fragments, pinned in regs (B-operand of S^T)
#pragma unroll
    for (int qs = 0; qs < 2; ++qs)
#pragma unroll
        for (int ds = 0; ds < 2; ++ds)
            qa[qs][ds] = *(const f16x8*)&Ps[(wv * 32 + qs * 16 + lm) * 64
                                            + (((ds * 4 + quad) ^ rs) << 3)];
    // wave 0's P region overlaps wave 1's Q-fragment rows -> barrier before
    // any wave starts writing P
    __syncthreads();

    f32x4 oacc[2][4];
#pragma unroll
    for (int i = 0; i < 2; ++i)
#pragma unroll
        for (int j = 0; j < 4; ++j) oacc[i][j] = (f32x4){0.f, 0.f, 0.f, 0.f};

    f16* Pw = Ps + wv * (32 * 72);    // per-wave padded P region

    for (int it = 0; it < SEQ / 64; ++it) {
        const int cur = it & 1, nxt = cur ^ 1;
        if (it + 1 < SEQ / 64) {
            const int k0n = (it + 1) * 64;
#pragma unroll
            for (int i = 0; i < 2; ++i) {
                int g = wv * 2 + i;
                async16(&Ks[nxt][g * 512],
                        Kh + base + (size_t)(k0n + g * 8 + grow) * HDIM + gsw);
                async16(&Vs[nxt][g * 512],
                        Vt + base + (size_t)(g * 8 + grow) * SEQ + k0n + gsw);
            }
            if (wv == 0) async4(&Ls[nxt][0], lgv + (size_t)bh * SEQ + k0n + lane);
        }

        // S^T tiles: D[m=k][n=q] = K . Q^T; exp2(s*log2e/10 + lg) -> P[q][k]
#pragma unroll
        for (int ct = 0; ct < 4; ++ct) {
            int krow = ct * 16 + lm;
            f16x8 kf0 = *(const f16x8*)&Ks[cur][krow * 64 + ((quad ^ rs) << 3)];
            f16x8 kf1 = *(const f16x8*)&Ks[cur][krow * 64 + (((4 + quad) ^ rs) << 3)];
            float lgr[4];
#pragma unroll
            for (int r = 0; r < 4; ++r) lgr[r] = Ls[cur][ct * 16 + quad * 4 + r];
#pragma unroll
            for (int qs = 0; qs < 2; ++qs) {
                f32x4 s4 = (f32x4){0.f, 0.f, 0.f, 0.f};
                s4 = mfma16(kf0, qa[qs][0], s4);
                s4 = mfma16(kf1, qa[qs][1], s4);
                f16x4 pk;
#pragma unroll
                for (int r = 0; r < 4; ++r)
                    pk[r] = (f16)fast_exp2(s4[r] * LOG2E_10 + lgr[r]);
                // row q = qs*16+lm, cols k = ct*16+quad*4..+3 (contiguous, 8B)
                *(f16x4*)&Pw[(qs * 16 + lm) * 72 + ct * 16 + quad * 4] = pk;
            }
        }
        // PV: D[m=q][n=d] = P @ Vt  (same-wave DS ordering makes P visible)
#pragma unroll
        for (int ks = 0; ks < 2; ++ks) {
            f16x8 pa0 = *(const f16x8*)&Pw[(lm) * 72 + ks * 32 + quad * 8];
            f16x8 pa1 = *(const f16x8*)&Pw[(16 + lm) * 72 + ks * 32 + quad * 8];
#pragma unroll
            for (int dt = 0; dt < 4; ++dt) {
                f16x8 vb = *(const f16x8*)&Vs[cur][(dt * 16 + lm) * 64
                                                   + (((ks * 4 + quad) ^ rs) << 3)];
                oacc[0][dt] = mfma16(pa0, vb, oacc[0][dt]);
                oacc[1][dt] = mfma16(pa1, vb, oacc[1][dt]);
            }
        }
        __syncthreads();   // drains stage vmcnt (after compute) + buffer reuse
    }

    const float inv1024 = 1.0f / 1024.0f;
#pragma unroll
    for (int qt = 0; qt < 2; ++qt)
#pragma unroll
        for (int dt = 0; dt < 4; ++dt) {
            int col = h * HDIM + dt * 16 + lm;
#pragma unroll
            for (int r = 0; r < 4; ++r) {
                int s = q0 + wv * 32 + qt * 16 + quad * 4 + r;
                out[((size_t)b * SEQ + s) * EMBED + col] = oacc[qt][dt][r] * inv1024;
            }
        }
}

extern "C" void kernel_launch(void* const* d_in, const int* in_sizes, int n_in,
                              void* d_out, int out_size, void* d_ws, size_t ws_size,
                              hipStream_t stream) {
    const float* x  = (const float*)d_in[0];
    const float* Wq = (const float*)d_in[1];
    const float* bq = (const float*)d_in[2];
    const float* Wk = (const float*)d_in[3];
    const float* bk = (const float*)d_in[4];
    const float* Wv = (const float*)d_in[5];
    const float* bv = (const float*)d_in[6];
    float* out = (float*)d_out;

    f16* xh = (f16*)d_ws;                          // 8388608
    f16* Wh = xh + (size_t)ROWS * EMBED;           // 3145728
    f16* Qh = Wh + (size_t)3 * EMBED * EMBED;      // 8388608
    f16* Kh = Qh + (size_t)BH * SEQ * HDIM;        // 8388608
    f16* Vt = Kh + (size_t)BH * SEQ * HDIM;        // 8388608
    float* lgv = (float*)(Vt + (size_t)BH * SEQ * HDIM);   // 131072 fp32
    // total ws use ~70.5 MB

    cvt_kernel<<<(NX4 + 3 * NW4) / 256, 256, 0, stream>>>(x, Wq, Wk, Wv, xh, Wh);
    proj_kernel<<<dim3(ROWS / 128, 3 * EMBED / 128), 256, 0, stream>>>(
        xh, Wh, bq, bk, bv, Qh, Kh, Vt);
    stats_kernel<<<dim3(SEQ / 128 * BH), 256, 0, stream>>>(Qh, Kh, lgv);
    out_kernel<<<dim3(SEQ / 128 * BH), 256, 0, stream>>>(Qh, Kh, Vt, lgv, out);
}

// Round 4
// 300.785 us; speedup vs baseline: 1.0848x; 1.0848x over previous
//
#include <hip/hip_runtime.h>
#include <math.h>

#define SEQ    2048
#define EMBED  1024
#define HEADS  16
#define HDIM   64
#define BATCH  4
#define ROWS   (BATCH * SEQ)    // 8192
#define BH     (BATCH * HEADS)  // 64

typedef _Float16 f16;
typedef __attribute__((ext_vector_type(8))) _Float16 f16x8;
typedef __attribute__((ext_vector_type(4))) _Float16 f16x4;
typedef __attribute__((ext_vector_type(4))) float    f32x4;

#define LOG2E_10 0.14426950408889634f   // log2(e)/10

// fast 2^x / log2(x) via the HW transcendental unit
__device__ __forceinline__ float fast_exp2(float x) { return __builtin_amdgcn_exp2f(x); }
__device__ __forceinline__ float fast_log2(float x) { return __builtin_amdgcn_logf(x); }

// async global->LDS copy, 16B per lane. LDS dest = uniform base + lane*16.
__device__ __forceinline__ void async16(void* l, const void* g) {
    __builtin_amdgcn_global_load_lds(
        (__attribute__((address_space(1))) void*)(uintptr_t)g,
        (__attribute__((address_space(3))) void*)(uint32_t)(uintptr_t)l,
        16, 0, 0);
}
// 4B per lane (for small fp32 vectors like lg tiles)
__device__ __forceinline__ void async4(void* l, const void* g) {
    __builtin_amdgcn_global_load_lds(
        (__attribute__((address_space(1))) void*)(uintptr_t)g,
        (__attribute__((address_space(3))) void*)(uint32_t)(uintptr_t)l,
        4, 0, 0);
}

__device__ __forceinline__ f32x4 mfma16(f16x8 a, f16x8 b, f32x4 c) {
    return __builtin_amdgcn_mfma_f32_16x16x32_f16(a, b, c, 0, 0, 0);
}
// K=16 variant: A,B are f16x4; used for PV where P stays register-resident.
__device__ __forceinline__ f32x4 mfma16k16(f16x4 a, f16x4 b, f32x4 c) {
    return __builtin_amdgcn_mfma_f32_16x16x16f16(a, b, c, 0, 0, 0);
}

// ---------------------------------------------------------------------------
// Kernel 0: fp32 -> fp16 convert. x -> xh [8192][1024]; Wq/Wk/Wv -> Wh
// concatenated [3072][1024]. Memory-bound, ~15us.
// ---------------------------------------------------------------------------
#define NX4 (ROWS * EMBED / 4)          // 2097152
#define NW4 (EMBED * EMBED / 4)         // 262144
__global__ __launch_bounds__(256) void cvt_kernel(
    const float* __restrict__ x,
    const float* __restrict__ Wq, const float* __restrict__ Wk,
    const float* __restrict__ Wv,
    f16* __restrict__ xh, f16* __restrict__ Wh)
{
    int i = blockIdx.x * 256 + threadIdx.x;
    const float4* src; f16* dst; int j;
    if (i < NX4)              { src = (const float4*)x;  dst = xh;                j = i; }
    else if (i < NX4 + NW4)   { src = (const float4*)Wq; dst = Wh;                j = i - NX4; }
    else if (i < NX4 + 2*NW4) { src = (const float4*)Wk; dst = Wh + EMBED*EMBED;  j = i - NX4 - NW4; }
    else                      { src = (const float4*)Wv; dst = Wh + 2*EMBED*EMBED;j = i - NX4 - 2*NW4; }
    float4 v = src[j];
    f16x4 h;
    h[0] = (f16)v.x; h[1] = (f16)v.y; h[2] = (f16)v.z; h[3] = (f16)v.w;
    *(f16x4*)(dst + (size_t)j * 4) = h;
}

// ---------------------------------------------------------------------------
// Kernel 1: fused QKV projection GEMM (f16 MFMA, m97 structure, R2 form:
// single-buffer 2-barrier -- dbuf measured neutral-to-negative in R3).
// C[8192][3072] = xh @ Wh^T + bias. 128x128 tile, BK=32, global_load_lds w=16.
// Epilogue: Q,K -> [bh][s][d] fp16; V -> transposed Vt [bh][d][s] fp16.
// ---------------------------------------------------------------------------
__global__ __launch_bounds__(256) void proj_kernel(
    const f16* __restrict__ A,   // [8192][1024]
    const f16* __restrict__ W,   // [3072][1024]
    const float* __restrict__ bq, const float* __restrict__ bk,
    const float* __restrict__ bv,
    f16* __restrict__ Qh, f16* __restrict__ Kh, f16* __restrict__ Vt)
{
    __shared__ f16 As[128 * 32];   // [row][32k], rows 64B, unpadded (glds layout)
    __shared__ f16 Bs[128 * 32];

    const int t = threadIdx.x, wv = t >> 6, lane = t & 63;
    const int lm = lane & 15, quad = lane >> 4;
    const int r0 = blockIdx.x * 128, c0 = blockIdx.y * 128;
    const int wm = wv & 1, wn = wv >> 1;

    const int srow = wv * 32 + (lane >> 2);
    const int sch  = (lane & 3) * 8;     // f16 units (16B chunks)
    const f16* gA = A + (size_t)(r0 + srow) * EMBED + sch;
    const f16* gB = W + (size_t)(c0 + srow) * EMBED + sch;
    f16* lA = As + wv * 1024;
    f16* lB = Bs + wv * 1024;

    f32x4 acc[4][4];
#pragma unroll
    for (int i = 0; i < 4; ++i)
#pragma unroll
        for (int j = 0; j < 4; ++j) acc[i][j] = (f32x4){0.f, 0.f, 0.f, 0.f};

    for (int kk = 0; kk < EMBED; kk += 32) {
        __syncthreads();
        async16(lA,        gA + kk);
        async16(lA + 512,  gA + 16 * EMBED + kk);
        async16(lB,        gB + kk);
        async16(lB + 512,  gB + 16 * EMBED + kk);
        __syncthreads();

        f16x8 af[4], bf[4];
#pragma unroll
        for (int i = 0; i < 4; ++i)
            af[i] = *(const f16x8*)&As[(wm * 64 + i * 16 + lm) * 32 + quad * 8];
#pragma unroll
        for (int i = 0; i < 4; ++i)
            bf[i] = *(const f16x8*)&Bs[(wn * 64 + i * 16 + lm) * 32 + quad * 8];
#pragma unroll
        for (int mi = 0; mi < 4; ++mi)
#pragma unroll
            for (int ni = 0; ni < 4; ++ni)
                acc[mi][ni] = mfma16(af[mi], bf[ni], acc[mi][ni]);
    }

    const int z = c0 >> 10;              // 0=Q 1=K 2=V (128 | 1024 so no straddle)
    const float* bias = (z == 0) ? bq : (z == 1) ? bk : bv;
#pragma unroll
    for (int ni = 0; ni < 4; ++ni) {
        int col = c0 + wn * 64 + ni * 16 + lm;
        int cz  = col & 1023;
        float bb = bias[cz];
        int h = cz >> 6, d = cz & 63;
#pragma unroll
        for (int mi = 0; mi < 4; ++mi) {
            int rbase = r0 + wm * 64 + mi * 16 + quad * 4;
            int b = rbase >> 11, s = rbase & 2047;   // 4 rows stay in same b
            if (z < 2) {
                f16* O = (z == 0) ? Qh : Kh;
                size_t base = ((size_t)(b * HEADS + h) * SEQ + s) * HDIM + d;
#pragma unroll
                for (int r = 0; r < 4; ++r)
                    O[base + (size_t)r * HDIM] = (f16)(acc[mi][ni][r] + bb);
            } else {
                f16x4 pk;
#pragma unroll
                for (int r = 0; r < 4; ++r) pk[r] = (f16)(acc[mi][ni][r] + bb);
                *(f16x4*)&Vt[((size_t)(b * HEADS + h) * HDIM + d) * SEQ + s] = pk;
            }
        }
    }
}

// XCD swizzle decode: 1024 blocks, 8 XCDs. d = xcd + 8*(x + 16*ygrp):
// all 16 blocks sharing a bh land on one XCD (hw round-robins wgid % 8).
__device__ __forceinline__ void xcd_decode(int d, int& bh, int& x128) {
    int xcd  = d & 7;
    int r    = d >> 3;
    x128     = (r & 15) * 128;
    bh       = (r >> 4) * 8 + xcd;
}

// ---------------------------------------------------------------------------
// Kernel 2: column stats. lg[bh][k] = 10 - log2( sum_q exp(S[q,k]/10) ).
// R2 form (single-buffer, 2-barrier: occupancy > pipelining here) + XCD
// swizzle. 128B-row tiles chunk-XOR-swizzled via pre-swizzled global source.
// ---------------------------------------------------------------------------
__global__ __launch_bounds__(256) void stats_kernel(
    const f16* __restrict__ Qh, const f16* __restrict__ Kh,
    float* __restrict__ lgv)
{
    __shared__ f16 Ks[128 * 64];   // [kcol][d] rows 128B, chunk-swizzled
    __shared__ f16 Qs[64 * 64];    // [q][d], chunk-swizzled

    const int t = threadIdx.x, wv = t >> 6, lane = t & 63;
    const int lm = lane & 15, quad = lane >> 4;
    int bh, k0;
    xcd_decode(blockIdx.x, bh, k0);
    const int grow = lane >> 3;
    const int gsw  = ((lane & 7) ^ grow) * 8;
    const int rs   = lm & 7;
    const size_t base = (size_t)bh * SEQ * HDIM;

#pragma unroll
    for (int i = 0; i < 4; ++i) {
        int g = wv * 4 + i;
        async16(Ks + g * 512, Kh + base + (size_t)(k0 + g * 8 + grow) * HDIM + gsw);
    }
    __syncthreads();

    f16x8 kf[2][2];   // [coltile][dstep] -- stays in registers all sweep
#pragma unroll
    for (int ct = 0; ct < 2; ++ct)
#pragma unroll
        for (int ds = 0; ds < 2; ++ds)
            kf[ct][ds] = *(const f16x8*)&Ks[(wv * 32 + ct * 16 + lm) * 64
                                            + (((ds * 4 + quad) ^ rs) << 3)];

    float cs0 = 0.f, cs1 = 0.f;
    for (int q0 = 0; q0 < SEQ; q0 += 64) {
        __syncthreads();
#pragma unroll
        for (int i = 0; i < 2; ++i) {
            int g = wv * 2 + i;
            async16(Qs + g * 512, Qh + base + (size_t)(q0 + g * 8 + grow) * HDIM + gsw);
        }
        __syncthreads();
#pragma unroll
        for (int qt = 0; qt < 4; ++qt) {
            f16x8 a0 = *(const f16x8*)&Qs[(qt * 16 + lm) * 64 + ((quad ^ rs) << 3)];
            f16x8 a1 = *(const f16x8*)&Qs[(qt * 16 + lm) * 64 + (((4 + quad) ^ rs) << 3)];
            f32x4 c0v = (f32x4){0.f, 0.f, 0.f, 0.f};
            f32x4 c1v = (f32x4){0.f, 0.f, 0.f, 0.f};
            c0v = mfma16(a0, kf[0][0], c0v); c0v = mfma16(a1, kf[0][1], c0v);
            c1v = mfma16(a0, kf[1][0], c1v); c1v = mfma16(a1, kf[1][1], c1v);
#pragma unroll
            for (int r = 0; r < 4; ++r) {
                cs0 += fast_exp2(c0v[r] * LOG2E_10);
                cs1 += fast_exp2(c1v[r] * LOG2E_10);
            }
        }
    }
    cs0 += __shfl_xor(cs0, 16, 64); cs0 += __shfl_xor(cs0, 32, 64);
    cs1 += __shfl_xor(cs1, 16, 64); cs1 += __shfl_xor(cs1, 32, 64);
    if (quad == 0) {
        lgv[(size_t)bh * SEQ + k0 + wv * 32 + lm]      = 10.0f - fast_log2(cs0);
        lgv[(size_t)bh * SEQ + k0 + wv * 32 + 16 + lm] = 10.0f - fast_log2(cs1);
    }
}

// ---------------------------------------------------------------------------
// Kernel 3: out[q,d] = (1/1024) * sum_k P''[q,k] * V[k,d],
//           P'' = exp2(S*log2e/10 + lg[k]).
// REGISTER-P redesign: waves split 2x2 over (q-half wq, k-half wk). Each wave
// computes S^T = K.Q^T for its 16-wide k sub-tiles; the S^T C-layout
// (col=q=lm, row=k=quad*4+r) IS the A-fragment layout of 16x16x16 MFMA, so
// P feeds PV straight from registers -- no LDS P roundtrip at all.
// Per-wave-iter DS: 4 b128 (K) + 8 b64 (V) + 2 b128-broadcast (lg) ~= 120 cy
// vs 384 before (the measured LDS-pipe roofline). Cross-wk partial-O summed
// once via LDS at the end. K/V double-buffered (free: VGPR-limited, not LDS),
// 1 barrier/iter. XCD swizzle kept (FETCH 141->25 MB measured).
// ---------------------------------------------------------------------------
__global__ __launch_bounds__(256) void out_kernel(
    const f16* __restrict__ Qh, const f16* __restrict__ Kh,
    const f16* __restrict__ Vt, const float* __restrict__ lgv,
    float* __restrict__ out)
{
    // f16-unit layout: [0,8192) Qs 128x64 | [8192,16384) Ks[2] |
    // [16384,24576) Vs[2] | [24576,25088) Ls[2][64] f32.
    // Epilogue red buffer (float[2][4096]) aliases [0,16384).
    __shared__ f16 L[24576 + 512];

    const int t = threadIdx.x, wv = t >> 6, lane = t & 63;
    const int lm = lane & 15, quad = lane >> 4;
    const int wq = wv >> 1, wk = wv & 1;
    int bh, q0;
    xcd_decode(blockIdx.x, bh, q0);
    const int b = bh >> 4, h = bh & 15;
    const int grow = lane >> 3;
    const int gsw  = ((lane & 7) ^ grow) * 8;   // swizzled 16B source chunk
    const int rs   = lm & 7;                    // read-side row swizzle key
    const size_t base = (size_t)bh * SEQ * HDIM;   // same stride for Qh/Kh/Vt

    f16* Qs = L;

    // stage Q[128][64] (swizzled), K/V/lg tile 0
#pragma unroll
    for (int i = 0; i < 4; ++i) {
        int g = wv * 4 + i;
        async16(Qs + g * 512, Qh + base + (size_t)(q0 + g * 8 + grow) * HDIM + gsw);
    }
#pragma unroll
    for (int i = 0; i < 2; ++i) {
        int g = wv * 2 + i;
        async16(L + 8192  + g * 512, Kh + base + (size_t)(g * 8 + grow) * HDIM + gsw);
        async16(L + 16384 + g * 512, Vt + base + (size_t)(g * 8 + grow) * SEQ + gsw);
    }
    if (wv == 0) async4((float*)(L + 24576), lgv + (size_t)bh * SEQ + lane);
    __syncthreads();

    // Q fragments (B-operand of S^T), pinned: wave's 64 q rows
    f16x8 qa[4][2];
#pragma unroll
    for (int qt = 0; qt < 4; ++qt)
#pragma unroll
        for (int ds = 0; ds < 2; ++ds)
            qa[qt][ds] = *(const f16x8*)&Qs[(wq * 64 + qt * 16 + lm) * 64
                                            + (((ds * 4 + quad) ^ rs) << 3)];

    f32x4 oacc[4][4];
#pragma unroll
    for (int i = 0; i < 4; ++i)
#pragma unroll
        for (int j = 0; j < 4; ++j) oacc[i][j] = (f32x4){0.f, 0.f, 0.f, 0.f};

    for (int it = 0; it < SEQ / 64; ++it) {
        const int cur = it & 1;
        if (it + 1 < SEQ / 64) {
            const int nxt = cur ^ 1, k0n = (it + 1) * 64;
            f16* Kb = L + 8192  + nxt * 4096;
            f16* Vb = L + 16384 + nxt * 4096;
#pragma unroll
            for (int i = 0; i < 2; ++i) {
                int g = wv * 2 + i;
                async16(Kb + g * 512, Kh + base + (size_t)(k0n + g * 8 + grow) * HDIM + gsw);
                async16(Vb + g * 512, Vt + base + (size_t)(g * 8 + grow) * SEQ + k0n + gsw);
            }
            if (wv == 0) async4((float*)(L + 24576) + nxt * 64,
                                lgv + (size_t)bh * SEQ + k0n + lane);
        }
        const f16* Kb = L + 8192  + cur * 4096;
        const f16* Vb = L + 16384 + cur * 4096;
        const float* Lb = (const float*)(L + 24576) + cur * 64;

#pragma unroll
        for (int ct = 0; ct < 2; ++ct) {
            const int kb = wk * 32 + ct * 16;   // k-local base of sub-tile
            // K A-frags: lane holds K[kb+lm][d = quad*8.. (+32 for ds=1)]
            f16x8 kf0 = *(const f16x8*)&Kb[(kb + lm) * 64 + ((quad ^ rs) << 3)];
            f16x8 kf1 = *(const f16x8*)&Kb[(kb + lm) * 64 + (((4 + quad) ^ rs) << 3)];
            // lg for lane's 4 k-rows (same-address per quad-group -> broadcast)
            f32x4 lg4 = *(const f32x4*)&Lb[kb + quad * 4];
            // V B-frags (K=16): lane needs V[kb+quad*4+j][dt*16+lm], contiguous
            // f16x4 in Vs[d][klocal]; chunk = kb/8 + quad/2, sub = (quad&1)*4
            const int vch = ((wk * 4 + ct * 2 + (quad >> 1)) ^ rs);
            f16x4 vb[4];
#pragma unroll
            for (int dt = 0; dt < 4; ++dt)
                vb[dt] = *(const f16x4*)&Vb[(dt * 16 + lm) * 64 + vch * 8 + (quad & 1) * 4];
#pragma unroll
            for (int qt = 0; qt < 4; ++qt) {
                f32x4 s4 = (f32x4){0.f, 0.f, 0.f, 0.f};
                s4 = mfma16(kf0, qa[qt][0], s4);
                s4 = mfma16(kf1, qa[qt][1], s4);
                // lane now holds S[q=wq*64+qt*16+lm][k=k0+kb+quad*4+r] --
                // exactly the 16x16x16 A-frag layout for PV. P stays in regs.
                f16x4 pa;
#pragma unroll
                for (int r = 0; r < 4; ++r)
                    pa[r] = (f16)fast_exp2(s4[r] * LOG2E_10 + lg4[r]);
#pragma unroll
                for (int dt = 0; dt < 4; ++dt)
                    oacc[qt][dt] = mfma16k16(pa, vb[dt], oacc[qt][dt]);
            }
        }
        __syncthreads();   // drains stage vmcnt + buffer reuse
    }

    // cross-wk reduction: wk=1 writes partials to LDS (aliases Qs/Ks, dead
    // now; last loop barrier ordered all reads), wk=0 adds + stores.
    float* red = (float*)L;   // [2][64*64]
    if (wk == 1) {
#pragma unroll
        for (int qt = 0; qt < 4; ++qt)
#pragma unroll
            for (int dt = 0; dt < 4; ++dt)
#pragma unroll
                for (int r = 0; r < 4; ++r)
                    red[wq * 4096 + (qt * 16 + quad * 4 + r) * 64 + dt * 16 + lm]
                        = oacc[qt][dt][r];
    }
    __syncthreads();
    if (wk == 0) {
        const float inv1024 = 1.0f / 1024.0f;
#pragma unroll
        for (int qt = 0; qt < 4; ++qt)
#pragma unroll
            for (int dt = 0; dt < 4; ++dt) {
                int col = h * HDIM + dt * 16 + lm;
#pragma unroll
                for (int r = 0; r < 4; ++r) {
                    int ql = qt * 16 + quad * 4 + r;
                    int s  = q0 + wq * 64 + ql;
                    float v = oacc[qt][dt][r]
                            + red[wq * 4096 + ql * 64 + dt * 16 + lm];
                    out[((size_t)b * SEQ + s) * EMBED + col] = v * inv1024;
                }
            }
    }
}

extern "C" void kernel_launch(void* const* d_in, const int* in_sizes, int n_in,
                              void* d_out, int out_size, void* d_ws, size_t ws_size,
                              hipStream_t stream) {
    const float* x  = (const float*)d_in[0];
    const float* Wq = (const float*)d_in[1];
    const float* bq = (const float*)d_in[2];
    const float* Wk = (const float*)d_in[3];
    const float* bk = (const float*)d_in[4];
    const float* Wv = (const float*)d_in[5];
    const float* bv = (const float*)d_in[6];
    float* out = (float*)d_out;

    f16* xh = (f16*)d_ws;                          // 8388608
    f16* Wh = xh + (size_t)ROWS * EMBED;           // 3145728
    f16* Qh = Wh + (size_t)3 * EMBED * EMBED;      // 8388608
    f16* Kh = Qh + (size_t)BH * SEQ * HDIM;        // 8388608
    f16* Vt = Kh + (size_t)BH * SEQ * HDIM;        // 8388608
    float* lgv = (float*)(Vt + (size_t)BH * SEQ * HDIM);   // 131072 fp32
    // total ws use ~70.5 MB

    cvt_kernel<<<(NX4 + 3 * NW4) / 256, 256, 0, stream>>>(x, Wq, Wk, Wv, xh, Wh);
    proj_kernel<<<dim3(ROWS / 128, 3 * EMBED / 128), 256, 0, stream>>>(
        xh, Wh, bq, bk, bv, Qh, Kh, Vt);
    stats_kernel<<<dim3(SEQ / 128 * BH), 256, 0, stream>>>(Qh, Kh, lgv);
    out_kernel<<<dim3(SEQ / 128 * BH), 256, 0, stream>>>(Qh, Kh, Vt, lgv, out);
}